// Round 9
// baseline (1582.007 us; speedup 1.0000x reference)
//
#include <hip/hip_runtime.h>
#include <hip/hip_bf16.h>
#include <stdint.h>

// LevelReasoning on MI355X — round 9: occupancy restructure.
// 112x128 tile, 256 threads (4 waves, 1x4), acc[7][2] -> ~150 regs/wave ->
// 3 blocks/CU (launch_bounds(256,3)). B operand read DIRECT from global/L2
// (weights <=1MB, L2-resident) -> LDS = A-only 28KB dbuf. Single barrier +
// vmcnt(0) per K-tile (r6 scheme). All GEMMs unified in one template;
// stats fused in gemm1/attn epilogues. Numerics identical to r8.

using bf16 = __hip_bfloat16;
typedef __attribute__((ext_vector_type(8))) short short8;
typedef __attribute__((ext_vector_type(4))) float f32x4;

__device__ inline uint16_t f2b_bits(float f) {
  bf16 h = __float2bfloat16(f);
  return __builtin_bit_cast(uint16_t, h);
}
__device__ inline float b2f_bits(uint16_t u) { return __uint_as_float(((uint32_t)u) << 16); }
__device__ inline float bflo(uint32_t u) { return __uint_as_float((u & 0xffffu) << 16); }
__device__ inline float bfhi(uint32_t u) { return __uint_as_float(u & 0xffff0000u); }
__device__ inline void split2(float v, uint16_t& hi, uint16_t& lo) {
  hi = f2b_bits(v);
  lo = f2b_bits(v - b2f_bits(hi));
}
__device__ inline float h16(const uint4& u, int e) {
  uint32_t wrd = ((const uint32_t*)&u)[e >> 1];
  return (e & 1) ? bfhi(wrd) : bflo(wrd);
}

typedef const __attribute__((address_space(1))) void* gas_ptr;
typedef __attribute__((address_space(3))) void* las_ptr;
__device__ inline void gload16(const void* g, void* l) {
  __builtin_amdgcn_global_load_lds((gas_ptr)g, (las_ptr)l, 16, 0, 0);
}

// ---------------- fold weight to io-format: W' = g*W*diag(s), b' = g*(b + t@W.T) ----------------
__global__ __launch_bounds__(512) void fold_w_io(const float* __restrict__ Wsrc,
                                                 const float* __restrict__ bsrc,
                                                 const float* __restrict__ sv,
                                                 const float* __restrict__ tv,
                                                 const float* __restrict__ gamp,
                                                 char* __restrict__ Wio,
                                                 float* __restrict__ bout) {
  const int row = blockIdx.x, c = threadIdx.x;
  __shared__ float red[512];
  const float wv = Wsrc[(size_t)row * 512 + c];
  const float g = gamp ? gamp[0] : 1.0f;
  const float s = sv ? sv[c] : 1.0f;
  uint16_t hb, lb;
  split2(g * wv * s, hb, lb);
  char* p = Wio + (size_t)row * 2048 + (c >> 3) * 32 + (c & 7) * 2;
  *(uint16_t*)p = hb;
  *(uint16_t*)(p + 16) = lb;
  red[c] = tv ? wv * tv[c] : 0.0f;
  __syncthreads();
#pragma unroll
  for (int off = 256; off > 0; off >>= 1) {
    if (c < off) red[c] += red[c + off];
    __syncthreads();
  }
  if (c == 0) bout[row] = g * (bsrc[row] + red[0]);
}

// ---------------- 112x128-tile split GEMM, 4 waves, B direct-from-L2 ----------------
// AMODE 0: A io-format split bf16 (2KB rows). AMODE 1: A f32 (2KB rows), split in-reg.
// EPI 0: outf[row*N+col]=acc+bias. EPI 1: io-format out + stats partials.
// EPI 2: plain bf16 out, pitch 512.  NPASS: 3 = hh+hl+lh, 1 = hi*hi.
template <int AMODE, int EPI, int NPASS>
__global__ __launch_bounds__(256, 3) void sgemm(const char* __restrict__ A,
                                                const char* __restrict__ Wio,
                                                const float* __restrict__ bias,
                                                float* __restrict__ outf,
                                                char* __restrict__ outb,
                                                float* __restrict__ part, int N) {
  constexpr int A_BYTES = 112 * 128;  // 14336
  __shared__ __align__(16) char lds[2 * A_BYTES];
  const int tid = threadIdx.x, w = tid >> 6, l = tid & 63;

  // XCD-chunked bijective block swizzle (total blocks % 8 == 0 for all grids)
  const int nwgx = gridDim.x;
  const int raw = blockIdx.y * nwgx + blockIdx.x;
  const int cpx = (nwgx * gridDim.y) >> 3;
  const int work = (raw & 7) * cpx + (raw >> 3);
  const int bmidx = work / nwgx;
  const int bm = bmidx * 112;
  const int bn = (work % nwgx) * 128;

  // A staging: lane l covers row (i*8 + (l>>3)), inverse-swizzled 32B pair + 16B piece
  const int ssl = ((((l >> 1) & 3) ^ ((l >> 3) & 3)) << 5) | (((l & 1) ^ ((l >> 5) & 1)) << 4);
  const char* Asrc = A + (size_t)(bm + (l >> 3)) * 2048 + ssl;

  // fragment geometry: wave w owns cols [bn + w*32, +32)
  const int lrow = l & 15, lk = l >> 4;
  const int sw32 = (lk ^ (lrow & 3)) * 32;
  const int hi16 = ((lrow >> 2) & 1) * 16;
  const int afr = lrow * 128 + sw32;  // + mi*2048 (+hi16 / ^16)

  // B direct-global base (no swizzle): row = bn + w*32 + ni*16 + lrow, slot lk
  const char* Bfr = Wio + (size_t)(bn + w * 32 + lrow) * 2048 + lk * 32;

  f32x4 acc[7][2] = {};

  auto stage_a = [&](int buf, int t) {
    char* dst = lds + buf * A_BYTES;
    const char* src = Asrc + (size_t)t * 128;
#pragma unroll
    for (int k = 0; k < 4; ++k) {
      const int i = w + k * 4;  // 14 instrs of 8 rows across 4 waves
      if (k < 3 || w < 2) gload16(src + (size_t)i * 16384, dst + i * 1024);
    }
  };

#define LOADA(BASE, CNT)                                                         \
  {                                                                              \
    _Pragma("unroll") for (int u = 0; u < (CNT); ++u) {                          \
      const int mi = (BASE) + u;                                                 \
      if constexpr (AMODE == 0) {                                                \
        ah[u] = *(const short8*)(bp + afr + mi * 2048 + hi16);                   \
        if constexpr (NPASS == 3)                                                \
          al[u] = *(const short8*)(bp + afr + mi * 2048 + (hi16 ^ 16));          \
      } else {                                                                   \
        float4 f0 = *(const float4*)(bp + afr + mi * 2048 + hi16);               \
        float4 f1 = *(const float4*)(bp + afr + mi * 2048 + (hi16 ^ 16));        \
        const float fv[8] = {f0.x, f0.y, f0.z, f0.w, f1.x, f1.y, f1.z, f1.w};    \
        _Pragma("unroll") for (int e = 0; e < 8; ++e) {                          \
          uint16_t hb, lb;                                                       \
          split2(fv[e], hb, lb);                                                 \
          ah[u][e] = (short)hb;                                                  \
          al[u][e] = (short)lb;                                                  \
        }                                                                        \
      }                                                                          \
    }                                                                            \
  }

#define MFMAC(BASE, CNT)                                                         \
  {                                                                              \
    __builtin_amdgcn_s_setprio(1);                                               \
    _Pragma("unroll") for (int u = 0; u < (CNT); ++u)                            \
      _Pragma("unroll") for (int ni = 0; ni < 2; ++ni)                           \
        acc[(BASE) + u][ni] = __builtin_amdgcn_mfma_f32_16x16x32_bf16(           \
            ah[u], bh[ni], acc[(BASE) + u][ni], 0, 0, 0);                        \
    if constexpr (NPASS == 3) {                                                  \
      _Pragma("unroll") for (int u = 0; u < (CNT); ++u)                          \
        _Pragma("unroll") for (int ni = 0; ni < 2; ++ni)                         \
          acc[(BASE) + u][ni] = __builtin_amdgcn_mfma_f32_16x16x32_bf16(         \
              ah[u], bl[ni], acc[(BASE) + u][ni], 0, 0, 0);                      \
      _Pragma("unroll") for (int u = 0; u < (CNT); ++u)                          \
        _Pragma("unroll") for (int ni = 0; ni < 2; ++ni)                         \
          acc[(BASE) + u][ni] = __builtin_amdgcn_mfma_f32_16x16x32_bf16(         \
              al[u], bh[ni], acc[(BASE) + u][ni], 0, 0, 0);                      \
    }                                                                            \
    __builtin_amdgcn_s_setprio(0);                                               \
  }

  stage_a(0, 0);
  int cur = 0;
  for (int t = 0; t < 16; ++t) {
    asm volatile("s_waitcnt vmcnt(0)" ::: "memory");  // A tile t landed (per-wave)
    __builtin_amdgcn_s_barrier();
    asm volatile("" ::: "memory");

    const char* bp = lds + cur * A_BYTES;
    // B fragments straight from L2 (weights are hot after first row-block)
    short8 bh[2], bl[2];
#pragma unroll
    for (int ni = 0; ni < 2; ++ni) {
      const char* p = Bfr + (size_t)ni * 16 * 2048 + t * 128;
      bh[ni] = *(const short8*)p;
      if constexpr (NPASS == 3) bl[ni] = *(const short8*)(p + 16);
    }
    if (t < 15) stage_a(cur ^ 1, t + 1);

    short8 ah[4], al[4];
    LOADA(0, 4)
    MFMAC(0, 4)
    LOADA(4, 3)
    MFMAC(4, 3)
    cur ^= 1;
  }
#undef LOADA
#undef MFMAC

  float sni[2] = {}, qni[2] = {};
#pragma unroll
  for (int mi = 0; mi < 7; ++mi) {
    const int row = bm + mi * 16 + lk * 4;
#pragma unroll
    for (int ni = 0; ni < 2; ++ni) {
      const int col = bn + w * 32 + ni * 16 + lrow;
      const float bc = bias[col];
#pragma unroll
      for (int j = 0; j < 4; ++j) {
        const float vv = acc[mi][ni][j] + bc;
        if constexpr (EPI == 0) {
          outf[(size_t)(row + j) * N + col] = vv;
        } else if constexpr (EPI == 1) {
          uint16_t hb, lb;
          split2(vv, hb, lb);
          char* p = outb + (size_t)(row + j) * 2048 + (col >> 3) * 32 + (col & 7) * 2;
          *(uint16_t*)p = hb;
          *(uint16_t*)(p + 16) = lb;
          sni[ni] += vv;
          qni[ni] += vv * vv;
        } else {
          ((bf16*)outb)[(size_t)(row + j) * 512 + col] = __float2bfloat16(vv);
        }
      }
    }
  }

  if constexpr (EPI == 1) {
    // reduce over lk lanes; cols are disjoint across waves -> direct global write
#pragma unroll
    for (int ni = 0; ni < 2; ++ni) {
      float s = sni[ni], q = qni[ni];
      s += __shfl_xor(s, 16); q += __shfl_xor(q, 16);
      s += __shfl_xor(s, 32); q += __shfl_xor(q, 32);
      if (lk == 0) {
        const int col = bn + w * 32 + ni * 16 + lrow;
        part[(size_t)bmidx * 1024 + col] = s;
        part[(size_t)bmidx * 1024 + 512 + col] = q;
      }
    }
  }
}

// ---------------- stats reduce: part[n][1024] -> sv, tv ----------------
__global__ __launch_bounds__(64) void reduce_stats(const float* __restrict__ part, int n,
                                                   const float* __restrict__ g,
                                                   const float* __restrict__ bb,
                                                   float* __restrict__ sv,
                                                   float* __restrict__ tv) {
  const int c = blockIdx.x, k = threadIdx.x;
  float sum = 0.f, sq = 0.f;
  for (int i = k; i < n; i += 64) {
    const float* p = part + (size_t)i * 1024;
    sum += p[c];
    sq += p[512 + c];
  }
#pragma unroll
  for (int o = 32; o; o >>= 1) {
    sum += __shfl_xor(sum, o);
    sq += __shfl_xor(sq, o);
  }
  if (k == 0) {
    const float mean = sum * (1.0f / 114688.0f);
    const float var = sq * (1.0f / 114688.0f) - mean * mean;
    const float sc = g[c] * rsqrtf(var + 1e-5f);
    sv[c] = sc;
    tv[c] = bb[c] - mean * sc;
  }
}

// ---------------- fused attention + residual + relu (+ stats), in place on h ----------------
template <bool STATS>
__global__ __launch_bounds__(256) void attn_relu(const float* __restrict__ qkf,
                                                 const bf16* __restrict__ V,
                                                 char* __restrict__ Hio,
                                                 const float* __restrict__ sv,
                                                 const float* __restrict__ tv,
                                                 float* __restrict__ part) {
  __shared__ float smS[4][512], smQ[4][512];
  const int w = threadIdx.x >> 6, l = threadIdx.x & 63;
  const int b = blockIdx.x * 4 + w;
  const size_t base = (size_t)b * 7;

  float qv[7], kv[7];
#pragma unroll
  for (int i = 0; i < 7; ++i) {
    qv[i] = qkf[(base + i) * 128 + l];
    kv[i] = qkf[(base + i) * 128 + 64 + l];
  }
  float att[7][7];
#pragma unroll
  for (int i = 0; i < 7; ++i)
#pragma unroll
    for (int j = 0; j < 7; ++j) {
      float p = qv[i] * kv[j];
#pragma unroll
      for (int o = 32; o; o >>= 1) p += __shfl_xor(p, o);
      att[i][j] = p;
    }
#pragma unroll
  for (int i = 0; i < 7; ++i) {
    float m = att[i][0];
#pragma unroll
    for (int j = 1; j < 7; ++j) m = fmaxf(m, att[i][j]);
    float sum = 0.f;
#pragma unroll
    for (int j = 0; j < 7; ++j) {
      att[i][j] = expf(att[i][j] - m);
      sum += att[i][j];
    }
    const float inv = 1.0f / sum;
#pragma unroll
    for (int j = 0; j < 7; ++j) att[i][j] *= inv;
  }

  const float4 s0 = *(const float4*)&sv[l * 8], s1 = *(const float4*)&sv[l * 8 + 4];
  const float4 t0 = *(const float4*)&tv[l * 8], t1 = *(const float4*)&tv[l * 8 + 4];
  const float sarr[8] = {s0.x, s0.y, s0.z, s0.w, s1.x, s1.y, s1.z, s1.w};
  const float tarr[8] = {t0.x, t0.y, t0.z, t0.w, t1.x, t1.y, t1.z, t1.w};

  uint4 vpk[7];
#pragma unroll
  for (int j = 0; j < 7; ++j)
    vpk[j] = *(const uint4*)((const char*)V + (base + j) * 1024 + l * 16);

  float s8[8] = {}, q8[8] = {};
#pragma unroll
  for (int i = 0; i < 7; ++i) {
    char* hp = Hio + (base + i) * 2048 + l * 32;
    uint4 hh = *(const uint4*)hp;
    uint4 hl = *(const uint4*)(hp + 16);
    float o[8] = {};
#pragma unroll
    for (int j = 0; j < 7; ++j) {
      const float a = att[i][j];
#pragma unroll
      for (int e = 0; e < 8; ++e) o[e] += a * h16(vpk[j], e);
    }
    uint16_t oh[8], ol[8];
#pragma unroll
    for (int e = 0; e < 8; ++e) {
      const float hval = h16(hh, e) + h16(hl, e);
      const float r = fmaxf(o[e] + hval * sarr[e] + tarr[e], 0.f);
      if constexpr (STATS) { s8[e] += r; q8[e] += r * r; }
      split2(r, oh[e], ol[e]);
    }
    uint4 ph, pl;
#pragma unroll
    for (int k2 = 0; k2 < 4; ++k2) {
      ((uint32_t*)&ph)[k2] = (uint32_t)oh[2 * k2] | ((uint32_t)oh[2 * k2 + 1] << 16);
      ((uint32_t*)&pl)[k2] = (uint32_t)ol[2 * k2] | ((uint32_t)ol[2 * k2 + 1] << 16);
    }
    *(uint4*)hp = ph;
    *(uint4*)(hp + 16) = pl;
  }

  if constexpr (STATS) {
#pragma unroll
    for (int e = 0; e < 8; ++e) {
      smS[w][l * 8 + e] = s8[e];
      smQ[w][l * 8 + e] = q8[e];
    }
    __syncthreads();
    const int c = threadIdx.x * 2;
#pragma unroll
    for (int cc = 0; cc < 2; ++cc) {
      const int c2 = c + cc;
      part[(size_t)blockIdx.x * 1024 + c2] =
          smS[0][c2] + smS[1][c2] + smS[2][c2] + smS[3][c2];
      part[(size_t)blockIdx.x * 1024 + 512 + c2] =
          smQ[0][c2] + smQ[1][c2] + smQ[2][c2] + smQ[3][c2];
    }
  }
}

extern "C" void kernel_launch(void* const* d_in, const int* in_sizes, int n_in,
                              void* d_out, int out_size, void* d_ws, size_t ws_size,
                              hipStream_t stream) {
  const float* x  = (const float*)d_in[0];
  const float* Wt = (const float*)d_in[1];
  const float* bt = (const float*)d_in[2];
  const float *bng[3], *bnb[3], *Wq[3], *bq[3], *Wk[3], *bk[3], *Wv[3], *bv[3], *gam[3];
  for (int i = 0; i < 3; ++i) {
    int o = 3 + 9 * i;
    bng[i] = (const float*)d_in[o + 0];
    bnb[i] = (const float*)d_in[o + 1];
    Wq[i]  = (const float*)d_in[o + 2];
    bq[i]  = (const float*)d_in[o + 3];
    Wk[i]  = (const float*)d_in[o + 4];
    bk[i]  = (const float*)d_in[o + 5];
    Wv[i]  = (const float*)d_in[o + 6];
    bv[i]  = (const float*)d_in[o + 7];
    gam[i] = (const float*)d_in[o + 8];
  }
  const float* Wb = (const float*)d_in[30];
  const float* bb = (const float*)d_in[31];

  char* ws = (char*)d_ws;
  char*  Hio   = ws;                               // 235,929,600 (114688 x 2048B)
  char*  V     = ws + 235929600;                   // 117,440,512 (plain bf16)
  float* part  = (float*)(ws + 353370112);         // 16,777,216 (4096 x 1024 f32)
  float* sv    = (float*)(ws + 370147328);         // 2,048
  float* tv    = (float*)(ws + 370149376);         // 2,048
  char*  WqkIo = ws + 370151424;                   // 262,144
  float* bqkf  = (float*)(ws + 370413568);         // 2,048
  char*  WvIo  = ws + 370415616;                   // 1,048,576
  float* bvf   = (float*)(ws + 371464192);         // 2,048
  char*  WtIo  = ws + 371466240;                   // 1,048,576
  float* btf   = (float*)(ws + 372514816);         // 2,048
  char*  WbIo  = ws + 372516864;                   // 524,288 (256 rows io)
  float* bbf   = (float*)(ws + 373041152);         // 1,024
  float* qkf   = (float*)d_out;                    // 58.7 MB <= out bytes (117MB)

  // weight prep
  fold_w_io<<<512, 512, 0, stream>>>(Wt, bt, nullptr, nullptr, nullptr, WtIo, btf);
  fold_w_io<<<256, 512, 0, stream>>>(Wb, bb, nullptr, nullptr, nullptr, WbIo, bbf);

  // h0 = x @ Wt.T + bt  (split 3-pass; io out + stats partials)
  sgemm<1, 1, 3><<<dim3(4, 1024), 256, 0, stream>>>((const char*)x, WtIo, btf,
                                                    nullptr, Hio, part, 512);

  for (int i = 0; i < 3; ++i) {
    reduce_stats<<<512, 64, 0, stream>>>(part, i == 0 ? 1024 : 4096,
                                         bng[i], bnb[i], sv, tv);
    fold_w_io<<<64, 512, 0, stream>>>(Wq[i], bq[i], sv, tv, nullptr, WqkIo, bqkf);
    fold_w_io<<<64, 512, 0, stream>>>(Wk[i], bk[i], sv, tv, nullptr,
                                      WqkIo + (size_t)64 * 2048, bqkf + 64);
    fold_w_io<<<512, 512, 0, stream>>>(Wv[i], bv[i], sv, tv, gam[i], WvIo, bvf);
    // q|k = h @ Wqk'.T + b'  (split 3-pass; f32 out on d_out)
    sgemm<0, 0, 3><<<dim3(1, 1024), 256, 0, stream>>>(Hio, WqkIo, bqkf, qkf,
                                                      nullptr, nullptr, 128);
    // v' = h @ (gam*Wv*s)'.T + b''  (split 3-pass; plain bf16 out)
    sgemm<0, 2, 3><<<dim3(4, 1024), 256, 0, stream>>>(Hio, WvIo, bvf, nullptr,
                                                      V, nullptr, 512);
    // h = relu(att@v' + h*s + t) in place (+ stats partials for next layer)
    if (i < 2)
      attn_relu<true><<<4096, 256, 0, stream>>>(qkf, (const bf16*)V, Hio, sv, tv, part);
    else
      attn_relu<false><<<4096, 256, 0, stream>>>(qkf, (const bf16*)V, Hio, sv, tv, nullptr);
  }

  // out = h3_hi @ Wb.T + bb  (1-pass hi*hi == plain bf16; f32 out)
  sgemm<0, 0, 1><<<dim3(2, 1024), 256, 0, stream>>>(Hio, WbIo, bbf, (float*)d_out,
                                                    nullptr, nullptr, 256);
}